// Round 10
// baseline (91.096 us; speedup 1.0000x reference)
//
#include <hip/hip_runtime.h>
#include <math.h>

#define NUM_E 6
#define DIM 1024
#define HID 256
#define NTOK 32768
#define NPB 4096   // tokens per batch (N)
#define TTYPE_UNKNOWN 5
#define ONE_MINUS_ALPHA 0.775f
#define FLOOR_TERM 0.0375f     // alpha * (1/E)
#define GRP 8                  // tokens per MLP block (683 working blocks; W1-reuse lever)
#define KQ 256                 // K quarter per thread-group

// Closed-form top1 + hard-cap + combine for a probs vector of 6.
__device__ __forceinline__ void finalize_and_write(const float probs[NUM_E], float cap,
                                                   float* __restrict__ disp_out,
                                                   float* __restrict__ comb_out) {
    float v = probs[0];
    int bi = 0;
#pragma unroll
    for (int e = 1; e < NUM_E; ++e) {
        if (probs[e] > v) { v = probs[e]; bi = e; }
    }
    float excess = fmaxf(v - cap, 0.0f);
    float capped = v - excess;                 // min(v, cap)
    float hr_idx = fmaxf(cap - capped, 0.0f);
    float hsum = fmaxf(hr_idx + 5.0f * cap, 1e-8f);
    float disp[NUM_E];
    float other = excess * cap / hsum;
#pragma unroll
    for (int e = 0; e < NUM_E; ++e) disp[e] = other;
    disp[bi] = capped + excess * hr_idx / hsum;
    float s = 0.0f;
#pragma unroll
    for (int e = 0; e < NUM_E; ++e) s += disp[e];
    float inv = 1.0f / (s + 1e-8f);
#pragma unroll
    for (int e = 0; e < NUM_E; ++e) {
        disp_out[e] = disp[e];
        comb_out[e] = disp[e] * inv;
    }
}

// Known tokens -> final output directly; unknown -> compacted list.
__launch_bounds__(256)
__global__ void classify_kernel(const int* __restrict__ ttypes,
                                const int* __restrict__ tarr,
                                const float* __restrict__ base,
                                float* __restrict__ out,
                                int* __restrict__ cnt,
                                int* __restrict__ list) {
    int i = blockIdx.x * blockDim.x + threadIdx.x;
    if (i >= NTOK) return;
    int ty = ttypes[i];
    if (ty == TTYPE_UNKNOWN) {
        int pos = atomicAdd(cnt, 1);
        list[pos] = i;
        return;
    }
    int b = i / NPB;
    float tnorm = (float)tarr[b] / 1000.0f;
    float cap = 0.5f + 1.1f * tnorm;
    float probs[NUM_E];
#pragma unroll
    for (int e = 0; e < NUM_E; ++e)
        probs[e] = ONE_MINUS_ALPHA * base[ty * NUM_E + e] + FLOOR_TERM;
    finalize_and_write(probs, cap,
                       out + (size_t)i * NUM_E,
                       out + (size_t)NTOK * NUM_E + (size_t)i * NUM_E);
}

// Fused MLP gate, 1024 threads = 16 waves -> 2 blocks/CU (8 waves/SIMD).
// GRP=8 tokens staged once in 32 KB LDS; thread (col = tid&255, q = tid>>8)
// accumulates K-quarter [q*256, +256). Per-token LDS base pointers are
// loop-invariant (1 KB span -> ds_read imm offsets; minimal address VALU).
// K-partials combined via the aliased xs/hp LDS region.
__global__ __launch_bounds__(1024, 8)
void mlp_kernel(const float* __restrict__ tokens,
                const int* __restrict__ tarr,
                const float* __restrict__ W1,
                const float* __restrict__ b1,
                const float* __restrict__ W2,
                const float* __restrict__ b2,
                float* __restrict__ out,
                const int* __restrict__ cnt,
                const int* __restrict__ list) {
    __shared__ float smem[GRP * DIM];    // 32 KB: xs during K-loop, hp after
    __shared__ float w2s[HID * NUM_E];   // 6 KB
    __shared__ float ls[GRP][NUM_E];

    int count = cnt[0];
    int start = blockIdx.x * GRP;
    if (start >= count) return;
    int tid = threadIdx.x;

    float (*xs)[DIM] = (float (*)[DIM])smem;

    // Stage 8 token rows: 2048 float4 slots, 1024 threads -> 2 each, coalesced.
    {
        int slot = tid & 255;            // float4 slot within a row
        int rr = tid >> 8;               // 0..3
#pragma unroll
        for (int p = 0; p < 2; ++p) {
            int r = rr + p * 4;
            int idx = start + r;
            if (idx > count - 1) idx = count - 1;   // dup tail -> idempotent writes
            int tok = list[idx];
            const float4* src = reinterpret_cast<const float4*>(tokens + (size_t)tok * DIM);
            reinterpret_cast<float4*>(xs[r])[slot] = src[slot];
        }
    }
    for (int kk = tid; kk < HID * NUM_E; kk += 1024) w2s[kk] = W2[kk];
    __syncthreads();

    int col = tid & 255;
    int q = tid >> 8;                    // 0..3
    int kbase = q * KQ;

    float acc[GRP];
#pragma unroll
    for (int r = 0; r < GRP; ++r) acc[r] = 0.0f;

    // Loop-invariant bases: LDS per-token, global per-column-quarter.
    const float* xb[GRP];
#pragma unroll
    for (int r = 0; r < GRP; ++r) xb[r] = &xs[r][kbase];
    const float* w1p = W1 + (size_t)kbase * HID + col;

#pragma unroll 4
    for (int k = 0; k < KQ; k += 4) {
        float w0 = w1p[(k + 0) * HID];
        float w1_ = w1p[(k + 1) * HID];
        float w2_ = w1p[(k + 2) * HID];
        float w3_ = w1p[(k + 3) * HID];
#pragma unroll
        for (int r = 0; r < GRP; ++r) {
            float4 xq = *reinterpret_cast<const float4*>(xb[r] + k);  // broadcast b128, imm offset
            acc[r] = fmaf(xq.x, w0, acc[r]);
            acc[r] = fmaf(xq.y, w1_, acc[r]);
            acc[r] = fmaf(xq.z, w2_, acc[r]);
            acc[r] = fmaf(xq.w, w3_, acc[r]);
        }
    }
    __syncthreads();   // all xs reads done; re-purpose smem as hp[8][1024]

    float (*hp)[1024] = (float (*)[1024])smem;
#pragma unroll
    for (int r = 0; r < GRP; ++r) hp[r][tid] = acc[r];
    __syncthreads();

    // Combine K-quarters + exact GELU; write back in place (each thread
    // reads/writes only hp[r][tid] among the col<256 slots).
    if (tid < 256) {
        float bj = b1[tid];
        const float kc = 0.70710678118654752f;
#pragma unroll
        for (int r = 0; r < GRP; ++r) {
            float pre = hp[r][tid] + hp[r][tid + 256] + hp[r][tid + 512]
                      + hp[r][tid + 768] + bj;
            hp[r][tid] = 0.5f * pre * (1.0f + erff(pre * kc));
        }
    }
    __syncthreads();

    // Layer 2: 48 threads, one (token, expert) dot each (h = hp[r][0..255]).
    if (tid < GRP * NUM_E) {
        int r = tid / NUM_E, e = tid % NUM_E;
        float s = 0.0f;
        for (int j = 0; j < HID; j += 4) {
            float4 hq = *reinterpret_cast<const float4*>(&hp[r][j]);
            s = fmaf(hq.x, w2s[(j + 0) * NUM_E + e], s);
            s = fmaf(hq.y, w2s[(j + 1) * NUM_E + e], s);
            s = fmaf(hq.z, w2s[(j + 2) * NUM_E + e], s);
            s = fmaf(hq.w, w2s[(j + 3) * NUM_E + e], s);
        }
        ls[r][e] = (s + b2[e]) / 0.1f;   // temperature
    }
    __syncthreads();

    // Finalize per token
    if (tid < GRP && start + tid < count) {
        int tokidx = list[start + tid];
        int b = tokidx / NPB;
        float tnorm = (float)tarr[b] / 1000.0f;
        float cap = 0.5f + 1.1f * tnorm;
        float probs[NUM_E];
#pragma unroll
        for (int e = 0; e < NUM_E; ++e)
            probs[e] = ONE_MINUS_ALPHA * ls[tid][e] + FLOOR_TERM;
        finalize_and_write(probs, cap,
                           out + (size_t)tokidx * NUM_E,
                           out + (size_t)NTOK * NUM_E + (size_t)tokidx * NUM_E);
    }
}

extern "C" void kernel_launch(void* const* d_in, const int* in_sizes, int n_in,
                              void* d_out, int out_size, void* d_ws, size_t ws_size,
                              hipStream_t stream) {
    const float* tokens = (const float*)d_in[0];
    const int*   ttypes = (const int*)d_in[1];
    const int*   tarr   = (const int*)d_in[2];
    const float* W1     = (const float*)d_in[3];
    const float* b1     = (const float*)d_in[4];
    const float* W2     = (const float*)d_in[5];
    const float* b2     = (const float*)d_in[6];
    const float* base   = (const float*)d_in[7];
    float* out = (float*)d_out;

    int* cnt  = (int*)d_ws;
    int* list = (int*)d_ws + 64;   // 256 B offset; list worst case 128 KB

    hipMemsetAsync(cnt, 0, sizeof(int), stream);
    classify_kernel<<<NTOK / 256, 256, 0, stream>>>(ttypes, tarr, base, out, cnt, list);
    mlp_kernel<<<NTOK / GRP, 1024, 0, stream>>>(tokens, tarr, W1, b1, W2, b2,
                                                out, cnt, list);
}

// Round 11
// 69.945 us; speedup vs baseline: 1.3024x; 1.3024x over previous
//
#include <hip/hip_runtime.h>
#include <math.h>

#define NUM_E 6
#define DIM 1024
#define HID 256
#define NTOK 32768
#define NPB 4096   // tokens per batch (N)
#define TTYPE_UNKNOWN 5
#define ONE_MINUS_ALPHA 0.775f
#define FLOOR_TERM 0.0375f     // alpha * (1/E)
#define GRP 8                  // tokens per MLP block (683 working blocks; W1-reuse lever)
#define KSPLIT 8               // K segments (tid>>6), each 128 wide
#define KSPAN 128
#define CPT 4                  // columns per thread (LDS-read:FMA ratio lever)

// Closed-form top1 + hard-cap + combine for a probs vector of 6.
__device__ __forceinline__ void finalize_and_write(const float probs[NUM_E], float cap,
                                                   float* __restrict__ disp_out,
                                                   float* __restrict__ comb_out) {
    float v = probs[0];
    int bi = 0;
#pragma unroll
    for (int e = 1; e < NUM_E; ++e) {
        if (probs[e] > v) { v = probs[e]; bi = e; }
    }
    float excess = fmaxf(v - cap, 0.0f);
    float capped = v - excess;                 // min(v, cap)
    float hr_idx = fmaxf(cap - capped, 0.0f);
    float hsum = fmaxf(hr_idx + 5.0f * cap, 1e-8f);
    float disp[NUM_E];
    float other = excess * cap / hsum;
#pragma unroll
    for (int e = 0; e < NUM_E; ++e) disp[e] = other;
    disp[bi] = capped + excess * hr_idx / hsum;
    float s = 0.0f;
#pragma unroll
    for (int e = 0; e < NUM_E; ++e) s += disp[e];
    float inv = 1.0f / (s + 1e-8f);
#pragma unroll
    for (int e = 0; e < NUM_E; ++e) {
        disp_out[e] = disp[e];
        comb_out[e] = disp[e] * inv;
    }
}

// Known tokens -> final output directly; unknown -> compacted list.
__launch_bounds__(256)
__global__ void classify_kernel(const int* __restrict__ ttypes,
                                const int* __restrict__ tarr,
                                const float* __restrict__ base,
                                float* __restrict__ out,
                                int* __restrict__ cnt,
                                int* __restrict__ list) {
    int i = blockIdx.x * blockDim.x + threadIdx.x;
    if (i >= NTOK) return;
    int ty = ttypes[i];
    if (ty == TTYPE_UNKNOWN) {
        int pos = atomicAdd(cnt, 1);
        list[pos] = i;
        return;
    }
    int b = i / NPB;
    float tnorm = (float)tarr[b] / 1000.0f;
    float cap = 0.5f + 1.1f * tnorm;
    float probs[NUM_E];
#pragma unroll
    for (int e = 0; e < NUM_E; ++e)
        probs[e] = ONE_MINUS_ALPHA * base[ty * NUM_E + e] + FLOOR_TERM;
    finalize_and_write(probs, cap,
                       out + (size_t)i * NUM_E,
                       out + (size_t)NTOK * NUM_E + (size_t)i * NUM_E);
}

// Fused MLP gate, 512 threads = 8 waves. GRP=8 tokens staged once in 32 KB LDS.
// Thread (cg = tid&63, ks = tid>>6) owns cols {cg,cg+64,cg+128,cg+192} over
// K-span [ks*128, +128): per 4-k step = 8 broadcast ds_read_b128 +
// 16 imm-offset W1 dwords + 128 FMA  ->  1 LDS instr per 16 FMA (4x round-10).
// K-partials reduced token-at-a-time through the aliased xs region.
__launch_bounds__(512)
__global__ void mlp_kernel(const float* __restrict__ tokens,
                           const int* __restrict__ tarr,
                           const float* __restrict__ W1,
                           const float* __restrict__ b1,
                           const float* __restrict__ W2,
                           const float* __restrict__ b2,
                           float* __restrict__ out,
                           const int* __restrict__ cnt,
                           const int* __restrict__ list) {
    __shared__ float smem[GRP * DIM];    // 32 KB: xs in K-loop; hp+hs after
    __shared__ float w2s[HID * NUM_E];   // 6 KB
    __shared__ float ls[GRP][NUM_E];

    int count = cnt[0];
    int start = blockIdx.x * GRP;
    if (start >= count) return;
    int tid = threadIdx.x;

    float (*xs)[DIM] = (float (*)[DIM])smem;

    // Stage 8 token rows: 2048 float4 slots, 512 threads -> 4 each, coalesced.
    {
        int slot = tid & 255;            // float4 slot within a row
        int rr = tid >> 8;               // 0..1
#pragma unroll
        for (int p = 0; p < 4; ++p) {
            int r = rr * 4 + p;
            int idx = start + r;
            if (idx > count - 1) idx = count - 1;   // dup tail -> idempotent writes
            int tok = list[idx];
            const float4* src = reinterpret_cast<const float4*>(tokens + (size_t)tok * DIM);
            reinterpret_cast<float4*>(xs[r])[slot] = src[slot];
        }
    }
    for (int kk = tid; kk < HID * NUM_E; kk += 512) w2s[kk] = W2[kk];
    __syncthreads();

    int cg = tid & 63;                   // column group (cols cg + 64*c)
    int ks = tid >> 6;                   // 0..7
    int kbase = ks * KSPAN;

    float acc[GRP][CPT];
#pragma unroll
    for (int r = 0; r < GRP; ++r)
#pragma unroll
        for (int c = 0; c < CPT; ++c) acc[r][c] = 0.0f;

    const float* w1p = W1 + (size_t)kbase * HID + cg;   // + k*HID + 64*c at imm offsets
    const float* xb[GRP];
#pragma unroll
    for (int r = 0; r < GRP; ++r) xb[r] = &xs[r][kbase];

#pragma unroll 1
    for (int k = 0; k < KSPAN; k += 4) {
        // 16 W1 loads: lane-consecutive (cg), imm offsets (kk*HID + 64*c)
        float w[4][CPT];
        const float* wp = w1p + (size_t)k * HID;
#pragma unroll
        for (int kk = 0; kk < 4; ++kk)
#pragma unroll
            for (int c = 0; c < CPT; ++c)
                w[kk][c] = wp[kk * HID + 64 * c];
        // 8 broadcast b128 x-reads, 128 FMA
#pragma unroll
        for (int r = 0; r < GRP; ++r) {
            float4 xq = *reinterpret_cast<const float4*>(xb[r] + k);
#pragma unroll
            for (int c = 0; c < CPT; ++c) {
                acc[r][c] = fmaf(xq.x, w[0][c], acc[r][c]);
                acc[r][c] = fmaf(xq.y, w[1][c], acc[r][c]);
                acc[r][c] = fmaf(xq.z, w[2][c], acc[r][c]);
                acc[r][c] = fmaf(xq.w, w[3][c], acc[r][c]);
            }
        }
    }
    __syncthreads();   // all xs reads done; re-purpose smem

    // aliased region (floats): hp[8][256] @0 (8 KB), hs[8][257] @2048
    float (*hp)[HID] = (float (*)[HID])smem;
    float (*hs)[HID + 1] = (float (*)[HID + 1])(smem + 2048);

    const float kc = 0.70710678118654752f;
#pragma unroll 1
    for (int r = 0; r < GRP; ++r) {
        // write this token's partials: hp[ks][cg + 64*c]
#pragma unroll
        for (int c = 0; c < CPT; ++c) hp[ks][cg + 64 * c] = acc[r][c];
        __syncthreads();
        if (tid < HID) {
            float s = hp[0][tid];
#pragma unroll
            for (int q = 1; q < KSPLIT; ++q) s += hp[q][tid];
            float pre = s + b1[tid];
            hs[r][tid] = 0.5f * pre * (1.0f + erff(pre * kc));
        }
        __syncthreads();
    }

    // Layer 2: 48 threads, one (token, expert) dot each
    if (tid < GRP * NUM_E) {
        int r = tid / NUM_E, e = tid % NUM_E;
        float s = 0.0f;
        for (int j = 0; j < HID; ++j) s = fmaf(hs[r][j], w2s[j * NUM_E + e], s);
        ls[r][e] = (s + b2[e]) / 0.1f;   // temperature
    }
    __syncthreads();

    // Finalize per token
    if (tid < GRP && start + tid < count) {
        int tokidx = list[start + tid];
        int b = tokidx / NPB;
        float tnorm = (float)tarr[b] / 1000.0f;
        float cap = 0.5f + 1.1f * tnorm;
        float probs[NUM_E];
#pragma unroll
        for (int e = 0; e < NUM_E; ++e)
            probs[e] = ONE_MINUS_ALPHA * ls[tid][e] + FLOOR_TERM;
        finalize_and_write(probs, cap,
                           out + (size_t)tokidx * NUM_E,
                           out + (size_t)NTOK * NUM_E + (size_t)tokidx * NUM_E);
    }
}

extern "C" void kernel_launch(void* const* d_in, const int* in_sizes, int n_in,
                              void* d_out, int out_size, void* d_ws, size_t ws_size,
                              hipStream_t stream) {
    const float* tokens = (const float*)d_in[0];
    const int*   ttypes = (const int*)d_in[1];
    const int*   tarr   = (const int*)d_in[2];
    const float* W1     = (const float*)d_in[3];
    const float* b1     = (const float*)d_in[4];
    const float* W2     = (const float*)d_in[5];
    const float* b2     = (const float*)d_in[6];
    const float* base   = (const float*)d_in[7];
    float* out = (float*)d_out;

    int* cnt  = (int*)d_ws;
    int* list = (int*)d_ws + 64;   // 256 B offset; list worst case 128 KB

    hipMemsetAsync(cnt, 0, sizeof(int), stream);
    classify_kernel<<<NTOK / 256, 256, 0, stream>>>(ttypes, tarr, base, out, cnt, list);
    mlp_kernel<<<NTOK / GRP, 512, 0, stream>>>(tokens, tarr, W1, b1, W2, b2,
                                               out, cnt, list);
}